// Round 2
// baseline (535.657 us; speedup 1.0000x reference)
//
#include <hip/hip_runtime.h>
#include <hip/hip_bf16.h>

#define H 1024
#define V 50257
#define L 50
#define NB 256      // blocks  (<= 256 CUs; 16 waves/block -> worst case 2 blocks/CU fits 32-wave cap)
#define NT 1024     // threads per block

// ---------------------------------------------------------------------------
// Single-use grid barrier. Counter zeroed by hipMemsetAsync before launch.
// Co-residency: 256 blocks x 16 waves; CU capacity 32 waves -> even worst-case
// packing (2 blocks/CU on 128 CUs) keeps every block resident => no deadlock.
// ---------------------------------------------------------------------------
__device__ inline void gridbar(unsigned* cnt) {
    __syncthreads();
    if (threadIdx.x == 0) {
        __threadfence();                       // make block's writes device-visible
        atomicAdd(cnt, 1u);                    // device-scope by default
        while (__hip_atomic_load(cnt, __ATOMIC_ACQUIRE, __HIP_MEMORY_SCOPE_AGENT) < NB)
            __builtin_amdgcn_s_sleep(2);
        __threadfence();
    }
    __syncthreads();
}

__global__ __launch_bounds__(NT, 4) void fused_decoder(
    const int* __restrict__ input_ids, const float* __restrict__ hidden,
    const float* __restrict__ enc,     const float* __restrict__ emb,
    const float* __restrict__ attn_w,  const float* __restrict__ attn_b,
    const float* __restrict__ comb_w,  const float* __restrict__ comb_b,
    const float* __restrict__ w_ih,    const float* __restrict__ w_hh,
    const float* __restrict__ b_ih,    const float* __restrict__ b_hh,
    const float* __restrict__ out_w,   const float* __restrict__ out_b,
    float* __restrict__ out, float* __restrict__ ws, unsigned* __restrict__ bar)
{
    __shared__ float smem[2048 + 192];
    const int tid  = threadIdx.x;
    const int bid  = blockIdx.x;
    const int wave = tid >> 6, lane = tid & 63;

    float* ws_scores = ws;            // 64
    float* ws_app    = ws + 64;       // H
    float* ws_x1     = ws_app + H;    // H
    float* ws_h1     = ws_x1 + H;     // H
    float* ws_x2     = ws_h1 + H;     // H
    float* ws_h2     = ws_x2 + H;     // H
    float* ws_part   = ws_h2 + H;     // 4096

    const int token = input_ids[0];
    const float* embrow = emb + (size_t)token * H;

    // ---------------- A1: attention scores, one block per l --------------
    if (bid < L) {
        const float* arow = attn_w + (size_t)bid * 2 * H;
        float acc = 0.f;
        if (tid < 512) {
            float4 a = ((const float4*)arow)[tid];
            float4 x = (tid < 256) ? ((const float4*)embrow)[tid]
                                   : ((const float4*)hidden)[tid - 256];
            acc = a.x * x.x + a.y * x.y + a.z * x.z + a.w * x.w;
        }
        #pragma unroll
        for (int off = 32; off; off >>= 1) acc += __shfl_down(acc, off);
        if (tid < 512 && lane == 0) smem[wave] = acc;     // waves 0..7
        __syncthreads();
        if (tid == 0) {
            float s = 0.f;
            for (int w = 0; w < 8; ++w) s += smem[w];
            ws_scores[bid] = s + attn_b[bid];
        }
    }
    gridbar(bar + 0 * 16);

    // ---------------- A2: softmax (redundant/block) + applied slice ------
    {
        if (tid == 0) {
            float m = ws_scores[0];
            for (int l = 1; l < L; ++l) m = fmaxf(m, ws_scores[l]);
            float s = 0.f;
            for (int l = 0; l < L; ++l) { float e = expf(ws_scores[l] - m); smem[l] = e; s += e; }
            float inv = 1.f / s;
            for (int l = 0; l < L; ++l) smem[l] *= inv;
        }
        __syncthreads();
        if (tid < 4) {                               // 256 blocks x 4 = 1024 elems
            int j = bid * 4 + tid;
            float acc = 0.f;
            for (int l = 0; l < L; ++l) acc += smem[l] * enc[l * H + j];
            ws_app[j] = acc;
        }
        if (bid == 0 && tid >= 64 && tid < 64 + L)   // attn weights output
            out[V + H + (tid - 64)] = smem[tid - 64];
    }
    gridbar(bar + 1 * 16);

    // ---------------- B: comb matvec + relu. 4 rows/block, 4 waves/row ---
    {
        float4* sc4 = (float4*)smem;                 // [embedded | applied], 512 float4
        if (tid < 256)      sc4[tid]       = ((const float4*)embrow)[tid];
        else if (tid < 512) sc4[tid]       = ((const float4*)ws_app)[tid - 256];
        __syncthreads();
        int r = bid * 4 + (wave >> 2);
        int seg = wave & 3;                          // 128 float4 per segment
        const float4* wr = (const float4*)(comb_w + (size_t)r * 2 * H);
        float acc = 0.f;
        #pragma unroll
        for (int k = 0; k < 2; ++k) {
            int idx = seg * 128 + k * 64 + lane;
            float4 a = wr[idx], b = sc4[idx];
            acc += a.x * b.x + a.y * b.y + a.z * b.z + a.w * b.w;
        }
        #pragma unroll
        for (int off = 32; off; off >>= 1) acc += __shfl_down(acc, off);
        if (lane == 0) smem[2048 + wave] = acc;
        __syncthreads();
        if (tid < 4) {
            int rr = bid * 4 + tid;
            float s = smem[2048 + tid * 4] + smem[2048 + tid * 4 + 1]
                    + smem[2048 + tid * 4 + 2] + smem[2048 + tid * 4 + 3];
            ws_x1[rr] = fmaxf(s + comb_b[rr], 0.f);
        }
    }
    gridbar(bar + 2 * 16);

    // ---------------- C/D: two GRU layers --------------------------------
    for (int layer = 0; layer < 2; ++layer) {
        const float* x  = (layer == 0) ? ws_x1 : ws_x2;
        const float* hp = (layer == 0) ? hidden : ws_h1;
        float* h_out  = (layer == 0) ? ws_h1 : ws_h2;
        float* x_out  = (layer == 0) ? ws_x2 : nullptr;
        float* h_copy = (layer == 0) ? nullptr : out + V;

        float4* sx4 = (float4*)smem;                 // x: 256 float4
        float4* sh4 = (float4*)(smem + 1024);        // h: 256 float4
        if (tid < 256)      sx4[tid]       = ((const float4*)x)[tid];
        else if (tid < 512) sh4[tid - 256] = ((const float4*)hp)[tid - 256];
        __syncthreads();

        int r   = bid * 4 + (wave >> 2);
        int seg = wave & 3;
        int idx = seg * 64 + lane;                   // float4 index 0..255
        float4 xv = sx4[idx], hv = sh4[idx];
        const float4* m0 = (const float4*)(w_ih + (size_t)r * H);
        const float4* m1 = (const float4*)(w_ih + (size_t)(H + r) * H);
        const float4* m2 = (const float4*)(w_ih + (size_t)(2 * H + r) * H);
        const float4* m3 = (const float4*)(w_hh + (size_t)r * H);
        const float4* m4 = (const float4*)(w_hh + (size_t)(H + r) * H);
        const float4* m5 = (const float4*)(w_hh + (size_t)(2 * H + r) * H);
        float4 t;
        float a0, a1, a2, a3, a4, a5;
        t = m0[idx]; a0 = t.x * xv.x + t.y * xv.y + t.z * xv.z + t.w * xv.w;
        t = m1[idx]; a1 = t.x * xv.x + t.y * xv.y + t.z * xv.z + t.w * xv.w;
        t = m2[idx]; a2 = t.x * xv.x + t.y * xv.y + t.z * xv.z + t.w * xv.w;
        t = m3[idx]; a3 = t.x * hv.x + t.y * hv.y + t.z * hv.z + t.w * hv.w;
        t = m4[idx]; a4 = t.x * hv.x + t.y * hv.y + t.z * hv.z + t.w * hv.w;
        t = m5[idx]; a5 = t.x * hv.x + t.y * hv.y + t.z * hv.z + t.w * hv.w;
        #pragma unroll
        for (int off = 32; off; off >>= 1) {
            a0 += __shfl_down(a0, off); a1 += __shfl_down(a1, off);
            a2 += __shfl_down(a2, off); a3 += __shfl_down(a3, off);
            a4 += __shfl_down(a4, off); a5 += __shfl_down(a5, off);
        }
        if (lane == 0) {
            float* p = smem + 2048 + wave * 8;
            p[0] = a0; p[1] = a1; p[2] = a2; p[3] = a3; p[4] = a4; p[5] = a5;
        }
        __syncthreads();
        if (tid < 4) {
            int rr = bid * 4 + tid;
            float g0 = 0, g1 = 0, g2 = 0, g3 = 0, g4 = 0, g5 = 0;
            #pragma unroll
            for (int s = 0; s < 4; ++s) {
                float* p = smem + 2048 + (tid * 4 + s) * 8;
                g0 += p[0]; g1 += p[1]; g2 += p[2]; g3 += p[3]; g4 += p[4]; g5 += p[5];
            }
            float gxr = g0 + b_ih[rr],         ghr = g3 + b_hh[rr];
            float gxz = g1 + b_ih[H + rr],     ghz = g4 + b_hh[H + rr];
            float gxn = g2 + b_ih[2 * H + rr], ghn = g5 + b_hh[2 * H + rr];
            float rg = 1.f / (1.f + expf(-(gxr + ghr)));
            float zg = 1.f / (1.f + expf(-(gxz + ghz)));
            float ng = tanhf(gxn + rg * ghn);
            float hval = smem[1024 + rr];          // full h vector staged in LDS
            float hn = (1.f - zg) * ng + zg * hval;
            h_out[rr] = hn;
            if (x_out)  x_out[rr]  = fmaxf(hn, 0.f);
            if (h_copy) h_copy[rr] = hn;
        }
        gridbar(bar + (3 + layer) * 16);
    }

    // ---------------- E: vocab logits + exp partials ---------------------
    {
        float4* sh4 = (float4*)smem;
        if (tid < 256) sh4[tid] = ((const float4*)ws_h2)[tid];
        __syncthreads();
        int gw = bid * 16 + wave;                    // 0..4095
        float psum = 0.f;
        for (int v = gw; v < V; v += 4096) {
            const float4* wr = (const float4*)(out_w + (size_t)v * H);
            float acc = 0.f;
            #pragma unroll
            for (int k = 0; k < 4; ++k) {
                int idx = k * 64 + lane;
                float4 a = wr[idx], b = sh4[idx];
                acc += a.x * b.x + a.y * b.y + a.z * b.z + a.w * b.w;
            }
            #pragma unroll
            for (int off = 32; off; off >>= 1) acc += __shfl_down(acc, off);
            if (lane == 0) {
                float lg = acc + out_b[v];
                out[v] = lg;
                psum += expf(lg);
            }
        }
        if (lane == 0) ws_part[gw] = psum;           // all 4096 entries written
    }
    gridbar(bar + 5 * 16);

    // ---------------- F: redundant deterministic LSE + subtract ----------
    {
        float s = 0.f;
        for (int i = tid; i < 4096; i += NT) s += ws_part[i];
        smem[tid] = s;
        __syncthreads();
        for (int off = 512; off; off >>= 1) {
            if (tid < off) smem[tid] += smem[tid + off];
            __syncthreads();
        }
        float lse = logf(smem[0]);
        int g = bid * NT + tid;                      // 262144 threads >= V
        if (g < V) out[g] -= lse;
    }
}

// ---------------------------------------------------------------------------
extern "C" void kernel_launch(void* const* d_in, const int* in_sizes, int n_in,
                              void* d_out, int out_size, void* d_ws, size_t ws_size,
                              hipStream_t stream) {
    const int*   input_ids = (const int*)d_in[0];
    const float* hidden    = (const float*)d_in[1];
    const float* enc       = (const float*)d_in[2];
    const float* emb       = (const float*)d_in[3];
    const float* attn_w    = (const float*)d_in[4];
    const float* attn_b    = (const float*)d_in[5];
    const float* comb_w    = (const float*)d_in[6];
    const float* comb_b    = (const float*)d_in[7];
    const float* w_ih      = (const float*)d_in[8];
    const float* w_hh      = (const float*)d_in[9];
    const float* b_ih      = (const float*)d_in[10];
    const float* b_hh      = (const float*)d_in[11];
    const float* out_w     = (const float*)d_in[12];
    const float* out_b     = (const float*)d_in[13];

    float* out = (float*)d_out;                      // [V | H | L]
    float* ws  = (float*)d_ws;
    // float regions: scores 64 | app 1024 | x1 1024 | h1 1024 | x2 1024 | h2 1024 | part 4096
    unsigned* bar = (unsigned*)(ws + 64 + 5 * 1024 + 4096);

    hipMemsetAsync(bar, 0, 6 * 16 * sizeof(unsigned), stream);  // zero barrier counters
    fused_decoder<<<NB, NT, 0, stream>>>(input_ids, hidden, enc, emb, attn_w, attn_b,
                                         comb_w, comb_b, w_ih, w_hh, b_ih, b_hh,
                                         out_w, out_b, out, ws, bar);
}

// Round 3
// 430.554 us; speedup vs baseline: 1.2441x; 1.2441x over previous
//
#include <hip/hip_runtime.h>
#include <hip/hip_bf16.h>

#define H 1024
#define V 50257
#define L 50

// ---------------------------------------------------------------------------
// K1: attention scores — one block per l (50 blocks, 512 threads).
// scores[l] = attn_w[l,:] . [embedded, h0] + attn_b[l]
// ---------------------------------------------------------------------------
__global__ void scores_kernel(const int* __restrict__ input_ids,
                              const float* __restrict__ hidden,
                              const float* __restrict__ emb,
                              const float* __restrict__ attn_w,
                              const float* __restrict__ attn_b,
                              float* __restrict__ ws_scores) {
    __shared__ float s_part[8];
    const int tid = threadIdx.x;            // 512
    const int l   = blockIdx.x;
    const int wave = tid >> 6, lane = tid & 63;
    const int token = input_ids[0];

    float4 a = ((const float4*)(attn_w + (size_t)l * 2 * H))[tid];
    float4 x = (tid < 256) ? ((const float4*)(emb + (size_t)token * H))[tid]
                           : ((const float4*)hidden)[tid - 256];
    float acc = a.x * x.x + a.y * x.y + a.z * x.z + a.w * x.w;
    #pragma unroll
    for (int off = 32; off; off >>= 1) acc += __shfl_down(acc, off);
    if (lane == 0) s_part[wave] = acc;
    __syncthreads();
    if (tid == 0) {
        float s = 0.f;
        #pragma unroll
        for (int w = 0; w < 8; ++w) s += s_part[w];
        ws_scores[l] = s + attn_b[l];
    }
}

// ---------------------------------------------------------------------------
// K2: softmax (redundant per thread, deterministic) + applied.
// grid 4 x 256 = 1024 threads, thread j computes applied[j].
// Block 0 threads 0..49 also write the attn-weights output.
// ---------------------------------------------------------------------------
__global__ void applied_kernel(const float* __restrict__ ws_scores,
                               const float* __restrict__ enc,
                               float* __restrict__ ws_app,
                               float* __restrict__ out_attnw) {
    const int j = blockIdx.x * 256 + threadIdx.x;   // 0..1023
    float w[L];
    float m = ws_scores[0];
    #pragma unroll
    for (int l = 1; l < L; ++l) m = fmaxf(m, ws_scores[l]);
    float s = 0.f;
    #pragma unroll
    for (int l = 0; l < L; ++l) { w[l] = expf(ws_scores[l] - m); s += w[l]; }
    float inv = 1.f / s;
    float acc = 0.f;
    #pragma unroll
    for (int l = 0; l < L; ++l) { w[l] *= inv; acc += w[l] * enc[l * H + j]; }
    ws_app[j] = acc;
    if (blockIdx.x == 0 && threadIdx.x < L) out_attnw[threadIdx.x] = w[threadIdx.x];
}

// ---------------------------------------------------------------------------
// K3: comb matvec (H rows x 2H) + relu.  grid 256 x 256, wave-per-row.
// ---------------------------------------------------------------------------
__global__ void comb_kernel(const float* __restrict__ comb_w,
                            const float* __restrict__ comb_b,
                            const int* __restrict__ input_ids,
                            const float* __restrict__ emb,
                            const float* __restrict__ applied,
                            float* __restrict__ x1) {
    __shared__ __align__(16) float s_c[2 * H];
    const int tid = threadIdx.x;
    const int token = input_ids[0];
    ((float4*)s_c)[tid] = ((const float4*)(emb + (size_t)token * H))[tid];
    ((float4*)(s_c + H))[tid] = ((const float4*)applied)[tid];
    __syncthreads();

    const int wave = tid >> 6, lane = tid & 63;
    const int i = blockIdx.x * 4 + wave;   // 0..1023
    const float4* r4 = (const float4*)(comb_w + (size_t)i * 2 * H);
    const float4* c4 = (const float4*)s_c;
    float acc = 0.f;
    #pragma unroll
    for (int kk = 0; kk < 8; ++kk) {
        int k = kk * 64 + lane;
        float4 a = r4[k], b = c4[k];
        acc += a.x * b.x + a.y * b.y + a.z * b.z + a.w * b.w;
    }
    #pragma unroll
    for (int off = 32; off; off >>= 1) acc += __shfl_down(acc, off);
    if (lane == 0) x1[i] = fmaxf(acc + comb_b[i], 0.f);
}

// ---------------------------------------------------------------------------
// K4/K5: GRU cell. Each wave owns output element i, computes all 6 dots.
// grid 256 x 256 (4 waves/block -> 1024 rows).
// ---------------------------------------------------------------------------
__global__ void gru_kernel(const float* __restrict__ x,
                           const float* __restrict__ hprev,
                           const float* __restrict__ w_ih,
                           const float* __restrict__ w_hh,
                           const float* __restrict__ b_ih,
                           const float* __restrict__ b_hh,
                           float* __restrict__ h_out,
                           float* __restrict__ x_out,   // relu(h), nullable
                           float* __restrict__ h_copy)  // mirror to d_out, nullable
{
    __shared__ __align__(16) float s_x[H];
    __shared__ __align__(16) float s_h[H];
    const int tid = threadIdx.x;
    ((float4*)s_x)[tid] = ((const float4*)x)[tid];
    ((float4*)s_h)[tid] = ((const float4*)hprev)[tid];
    __syncthreads();

    const int wave = tid >> 6, lane = tid & 63;
    const int i = blockIdx.x * 4 + wave;   // 0..1023
    const float4* x4 = (const float4*)s_x;
    const float4* h4 = (const float4*)s_h;
    const float4* wr_x = (const float4*)(w_ih + (size_t)i * H);
    const float4* wz_x = (const float4*)(w_ih + (size_t)(H + i) * H);
    const float4* wn_x = (const float4*)(w_ih + (size_t)(2 * H + i) * H);
    const float4* wr_h = (const float4*)(w_hh + (size_t)i * H);
    const float4* wz_h = (const float4*)(w_hh + (size_t)(H + i) * H);
    const float4* wn_h = (const float4*)(w_hh + (size_t)(2 * H + i) * H);

    float ar = 0.f, az = 0.f, an = 0.f, br = 0.f, bz = 0.f, bn = 0.f;
    #pragma unroll
    for (int kk = 0; kk < 4; ++kk) {
        int k = kk * 64 + lane;
        float4 xv = x4[k], hv = h4[k], t;
        t = wr_x[k]; ar += t.x * xv.x + t.y * xv.y + t.z * xv.z + t.w * xv.w;
        t = wz_x[k]; az += t.x * xv.x + t.y * xv.y + t.z * xv.z + t.w * xv.w;
        t = wn_x[k]; an += t.x * xv.x + t.y * xv.y + t.z * xv.z + t.w * xv.w;
        t = wr_h[k]; br += t.x * hv.x + t.y * hv.y + t.z * hv.z + t.w * hv.w;
        t = wz_h[k]; bz += t.x * hv.x + t.y * hv.y + t.z * hv.z + t.w * hv.w;
        t = wn_h[k]; bn += t.x * hv.x + t.y * hv.y + t.z * hv.z + t.w * hv.w;
    }
    #pragma unroll
    for (int off = 32; off; off >>= 1) {
        ar += __shfl_down(ar, off); az += __shfl_down(az, off);
        an += __shfl_down(an, off); br += __shfl_down(br, off);
        bz += __shfl_down(bz, off); bn += __shfl_down(bn, off);
    }
    if (lane == 0) {
        float gxr = ar + b_ih[i],         ghr = br + b_hh[i];
        float gxz = az + b_ih[H + i],     ghz = bz + b_hh[H + i];
        float gxn = an + b_ih[2 * H + i], ghn = bn + b_hh[2 * H + i];
        float r = 1.f / (1.f + expf(-(gxr + ghr)));
        float z = 1.f / (1.f + expf(-(gxz + ghz)));
        float n = tanhf(gxn + r * ghn);
        float hn = (1.f - z) * n + z * s_h[i];
        h_out[i] = hn;
        if (x_out)  x_out[i]  = fmaxf(hn, 0.f);
        if (h_copy) h_copy[i] = hn;
    }
}

// ---------------------------------------------------------------------------
// K6: vocab logits -> d_out directly. Wave handles 2 consecutive rows with
// interleaved loads (8 in flight). Per-block partial sum of exp for lse.
// ---------------------------------------------------------------------------
__global__ void logits_kernel(const float* __restrict__ out_w,
                              const float* __restrict__ out_b,
                              const float* __restrict__ h,
                              float* __restrict__ out,       // d_out[0..V)
                              float* __restrict__ partials) {
    __shared__ __align__(16) float s_h[H];
    __shared__ float s_part[4];
    const int tid = threadIdx.x;
    ((float4*)s_h)[tid] = ((const float4*)h)[tid];
    __syncthreads();

    const int wave = tid >> 6, lane = tid & 63;
    const float4* h4 = (const float4*)s_h;
    const int v0 = blockIdx.x * 8 + wave * 2;
    const int v1 = v0 + 1;
    float acc0 = 0.f, acc1 = 0.f;
    const float4* w0 = (const float4*)(out_w + (size_t)v0 * H);
    const float4* w1 = (const float4*)(out_w + (size_t)v1 * H);
    if (v1 < V) {
        #pragma unroll
        for (int kk = 0; kk < 4; ++kk) {
            int k = kk * 64 + lane;
            float4 b = h4[k];
            float4 a0 = w0[k], a1 = w1[k];
            acc0 += a0.x * b.x + a0.y * b.y + a0.z * b.z + a0.w * b.w;
            acc1 += a1.x * b.x + a1.y * b.y + a1.z * b.z + a1.w * b.w;
        }
    } else if (v0 < V) {
        #pragma unroll
        for (int kk = 0; kk < 4; ++kk) {
            int k = kk * 64 + lane;
            float4 b = h4[k];
            float4 a0 = w0[k];
            acc0 += a0.x * b.x + a0.y * b.y + a0.z * b.z + a0.w * b.w;
        }
    }
    #pragma unroll
    for (int off = 32; off; off >>= 1) {
        acc0 += __shfl_down(acc0, off);
        acc1 += __shfl_down(acc1, off);
    }
    float psum = 0.f;
    if (lane == 0) {
        if (v0 < V) { float lg = acc0 + out_b[v0]; out[v0] = lg; psum += expf(lg); }
        if (v1 < V) { float lg = acc1 + out_b[v1]; out[v1] = lg; psum += expf(lg); }
        s_part[wave] = psum;
    }
    __syncthreads();
    if (tid == 0)
        partials[blockIdx.x] = s_part[0] + s_part[1] + s_part[2] + s_part[3];
}

// K7: reduce partial exp-sums -> log-sum-exp scalar (single block)
__global__ void lse_kernel(const float* __restrict__ partials, int n,
                           float* __restrict__ lse) {
    __shared__ float red[256];
    const int tid = threadIdx.x;
    float s = 0.f;
    for (int i = tid; i < n; i += 256) s += partials[i];
    red[tid] = s;
    __syncthreads();
    for (int off = 128; off; off >>= 1) {
        if (tid < off) red[tid] += red[tid + off];
        __syncthreads();
    }
    if (tid == 0) *lse = logf(red[0]);
}

// K8: in-place log_probs[v] = logits[v] - lse
__global__ void sub_kernel(float* __restrict__ out,
                           const float* __restrict__ lse) {
    const int v = blockIdx.x * 256 + threadIdx.x;
    if (v < V) out[v] -= *lse;
}

// ---------------------------------------------------------------------------
extern "C" void kernel_launch(void* const* d_in, const int* in_sizes, int n_in,
                              void* d_out, int out_size, void* d_ws, size_t ws_size,
                              hipStream_t stream) {
    const int*   input_ids = (const int*)d_in[0];
    const float* hidden    = (const float*)d_in[1];
    const float* enc       = (const float*)d_in[2];
    const float* emb       = (const float*)d_in[3];
    const float* attn_w    = (const float*)d_in[4];
    const float* attn_b    = (const float*)d_in[5];
    const float* comb_w    = (const float*)d_in[6];
    const float* comb_b    = (const float*)d_in[7];
    const float* w_ih      = (const float*)d_in[8];
    const float* w_hh      = (const float*)d_in[9];
    const float* b_ih      = (const float*)d_in[10];
    const float* b_hh      = (const float*)d_in[11];
    const float* out_w     = (const float*)d_in[12];
    const float* out_b     = (const float*)d_in[13];

    float* out = (float*)d_out;            // [V | H | L]
    float* ws  = (float*)d_ws;
    float* ws_scores = ws;                 // 64
    float* ws_app    = ws + 64;            // H
    float* ws_x1     = ws_app + H;         // H
    float* ws_h1     = ws_x1 + H;          // H
    float* ws_x2     = ws_h1 + H;          // H
    float* ws_h2     = ws_x2 + H;          // H
    float* ws_part   = ws_h2 + H;          // 6400
    float* ws_lse    = ws_part + 6400;     // 1

    const int nblk_logits = (V + 7) / 8;   // 6283

    scores_kernel<<<L, 512, 0, stream>>>(input_ids, hidden, emb, attn_w, attn_b,
                                         ws_scores);
    applied_kernel<<<4, 256, 0, stream>>>(ws_scores, enc, ws_app, out + V + H);
    comb_kernel<<<256, 256, 0, stream>>>(comb_w, comb_b, input_ids, emb, ws_app,
                                         ws_x1);
    gru_kernel<<<256, 256, 0, stream>>>(ws_x1, hidden, w_ih, w_hh, b_ih, b_hh,
                                        ws_h1, ws_x2, nullptr);
    gru_kernel<<<256, 256, 0, stream>>>(ws_x2, ws_h1, w_ih, w_hh, b_ih, b_hh,
                                        ws_h2, nullptr, out + V);
    logits_kernel<<<nblk_logits, 256, 0, stream>>>(out_w, out_b, ws_h2,
                                                   out, ws_part);
    lse_kernel<<<1, 256, 0, stream>>>(ws_part, nblk_logits, ws_lse);
    sub_kernel<<<(V + 255) / 256, 256, 0, stream>>>(out, ws_lse);
}